// Round 5
// baseline (293.429 us; speedup 1.0000x reference)
//
#include <hip/hip_runtime.h>
#include <math.h>

// ModulationIndex as MFMA GEMM, v5: T-quartered for 4 blocks/CU (32 waves),
// spill-free R3 phase structure, small code body (tile loop not unrolled).
// amp_sums[p*18+k, a] = sum_t onehot[pk, t] * amp[a, t]
// Grid 1024 = (group, t-quarter); 512 thr; ~25KB LDS -> 4 blocks/CU.
// 8 waves = 4 m-quarters x 2 k-halves. B = amp hi/lo f16 (lo*4096), single
// LDS buffer per tile (TC=128), prefetch next tile into regs during compute.

#define FP_ 10
#define FA_ 30
#define K_  18
#define T_  2048
#define TQ_ 512    // t per block
#define TC_ 128    // t per LDS tile
#define NTILE 4
#define RS_ 68     // u32 per amp row: 64 data + 4 pad
#define BSW_ 130   // u32 per bins row: 128 data + 2 pad
#define NT_ 512

#define OFF_BINS 128
#define OFF_AMP  (128 + 10 * BSW_ * 4)        // 5328
#define AMPSZ    (32 * RS_ * 4)               // 8704
#define LDS_BYTES 25472                       // red (128+25344) is the max user

typedef _Float16 half8 __attribute__((ext_vector_type(8)));
typedef float    f32x4 __attribute__((ext_vector_type(4)));

// onehot for 4 u8 bins in w vs replicated kb4: two u32 f16-pair masks
// (0x3C00 where bin==kb). zero-byte trick + v_perm spread + *0x78.
static __device__ __forceinline__ uint2 oh4(unsigned w, unsigned kb4) {
  const unsigned x = w ^ kb4;
  const unsigned t = (x & 0x7F7F7F7Fu) + 0x7F7F7F7Fu;
  const unsigned m = ~(t | x) & 0x80808080u;
  const unsigned p0 = __builtin_amdgcn_perm(0u, m, 0x04010400u) * 0x78u;
  const unsigned p1 = __builtin_amdgcn_perm(0u, m, 0x04030402u) * 0x78u;
  return make_uint2(p0, p1);
}

__global__ __launch_bounds__(NT_, 8)
void mi_main(const float* __restrict__ pha, const float* __restrict__ amp,
             float* __restrict__ ws) {
  extern __shared__ unsigned char smem[];
  float*    c_lds = (float*)smem;
  unsigned* binsw = (unsigned*)(smem + OFF_BINS);
  unsigned* amp_h = (unsigned*)(smem + OFF_AMP);
  unsigned* amp_l = (unsigned*)(smem + OFF_AMP + AMPSZ);
  float*    red   = (float*)(smem + 128);   // aliases bins+amp after K-loop

  const int tid  = threadIdx.x;
  const int lane = tid & 63;
  const int wv   = tid >> 6;
  const int quad = lane >> 4;
  const int lc   = lane & 15;
  const int mq   = wv & 3;    // m-quarter: rows mq*48..+47
  const int q2   = wv >> 2;   // k-half within tile

  const int bid  = blockIdx.x;
  const int g    = bid >> 2;          // bc*4 + s
  const int qt   = bid & 3;           // t-quarter
  const int s    = g & 3;
  const int bc   = g >> 2;
  const long pha_base = (long)bc * (FP_ * 4L * T_) + (long)s * T_ + qt * TQ_;
  const long amp_base = (long)bc * (FA_ * 4L * T_) + (long)s * T_ + qt * TQ_;

  // cutoffs: bit-exact np.linspace(-pi, pi, 19) (f64 math, f32 cast)
  if (tid < 19) {
    const double PI_D = 3.14159265358979323846264338327950288;
    const double step = (2.0 * PI_D) / 18.0;
    c_lds[tid] = (tid == 18) ? (float)PI_D : (float)(-PI_D + (double)tid * step);
  }
  // static B rows 30 (ones -> counts) / 31 (pad); written once, persists.
  if (tid < RS_) {
    amp_h[30 * RS_ + tid] = 0x3C003C00u;
    amp_h[31 * RS_ + tid] = 0u;
    amp_l[30 * RS_ + tid] = 0u;
    amp_l[31 * RS_ + tid] = 0u;
  }

  // issue tile-0 amp loads first: latency hides under bins phase
  const bool stager = tid < 480;
  const int a_row = tid >> 4;
  const int seg   = tid & 15;
  const float* gsrc = amp + amp_base + (long)a_row * (4L * T_) + seg * 8;
  float4 vreg[2];
  if (stager) {
    vreg[0] = *(const float4*)(gsrc);
    vreg[1] = *(const float4*)(gsrc + 4);
  }

  // --- bins: 1280 u32 words (u8 bins, 4 t each)
  const float PI_F    = 3.14159274101257324f;
  const float INVSTEP = 2.8647890f;
  #pragma unroll
  for (int it = 0; it < 3; ++it) {
    const int i = it * NT_ + tid;
    if (i < 1280) {
      const int p = i >> 7, w = i & 127;
      const float4 v = *(const float4*)(pha + pha_base + (long)p * (4L * T_) + w * 4);
      const float xs[4] = {v.x, v.y, v.z, v.w};
      unsigned pk = 0;
      #pragma unroll
      for (int j = 0; j < 4; ++j) {
        const float x = xs[j];
        int gi = (int)((x + PI_F) * INVSTEP);
        gi = min(17, max(0, gi));
        if (x <= c_lds[gi]) gi -= 1;        // searchsorted-left
        else if (x > c_lds[gi + 1]) gi += 1;
        gi = min(17, max(0, gi));
        pk |= ((unsigned)gi) << (8 * j);
      }
      binsw[p * BSW_ + w] = pk;
    }
  }

  // per-wave row tables
  int p_mt[3]; unsigned kb4_mt[3];
  #pragma unroll
  for (int mt = 0; mt < 3; ++mt) {
    const int row = mq * 48 + mt * 16 + lc;
    int p = row / 18; p = min(p, 9);
    const unsigned kb = (unsigned)(row - p * 18);   // >=18 on pad rows
    p_mt[mt] = p;
    kb4_mt[mt] = kb * 0x01010101u;
  }

  f32x4 acch[3][2], accl[3][2];
  #pragma unroll
  for (int mt = 0; mt < 3; ++mt) {
    acch[mt][0] = (f32x4){0.f,0.f,0.f,0.f}; acch[mt][1] = (f32x4){0.f,0.f,0.f,0.f};
    accl[mt][0] = (f32x4){0.f,0.f,0.f,0.f}; accl[mt][1] = (f32x4){0.f,0.f,0.f,0.f};
  }
  __syncthreads();   // bins + cutoffs + const rows visible

  #pragma unroll 1
  for (int tile = 0; tile < NTILE; ++tile) {
    // convert + write current tile (vreg) into the single LDS buffer
    if (stager) {
      unsigned hw[4], lw[4];
      #pragma unroll
      for (int j = 0; j < 2; ++j) {
        const float xv[4] = {vreg[j].x, vreg[j].y, vreg[j].z, vreg[j].w};
        #pragma unroll
        for (int e = 0; e < 4; e += 2) {
          _Float16 h0 = (_Float16)xv[e];
          _Float16 h1 = (_Float16)xv[e + 1];
          _Float16 l0 = (_Float16)((xv[e]     - (float)h0) * 4096.0f);
          _Float16 l1 = (_Float16)((xv[e + 1] - (float)h1) * 4096.0f);
          hw[j*2 + e/2] = (unsigned)__builtin_bit_cast(unsigned short, h0)
                        | ((unsigned)__builtin_bit_cast(unsigned short, h1) << 16);
          lw[j*2 + e/2] = (unsigned)__builtin_bit_cast(unsigned short, l0)
                        | ((unsigned)__builtin_bit_cast(unsigned short, l1) << 16);
        }
      }
      *(uint4*)&amp_h[a_row * RS_ + seg * 4] = make_uint4(hw[0], hw[1], hw[2], hw[3]);
      *(uint4*)&amp_l[a_row * RS_ + seg * 4] = make_uint4(lw[0], lw[1], lw[2], lw[3]);
    }
    __syncthreads();
    // prefetch next tile into regs; overlaps compute below
    if (stager && tile < NTILE - 1) {
      vreg[0] = *(const float4*)(gsrc + (tile + 1) * TC_);
      vreg[1] = *(const float4*)(gsrc + (tile + 1) * TC_ + 4);
    }

    #pragma unroll
    for (int ci = 0; ci < 2; ++ci) {
      const int cl   = q2 * 2 + ci;          // 32-t chunk 0..3 in tile
      const int boff = cl * 16 + quad * 4;
      const half8 bh0 = __builtin_bit_cast(half8, *(const uint4*)&amp_h[lc * RS_ + boff]);
      const half8 bh1 = __builtin_bit_cast(half8, *(const uint4*)&amp_h[(16 + lc) * RS_ + boff]);
      const half8 bl0 = __builtin_bit_cast(half8, *(const uint4*)&amp_l[lc * RS_ + boff]);
      const half8 bl1 = __builtin_bit_cast(half8, *(const uint4*)&amp_l[(16 + lc) * RS_ + boff]);
      const int widx = tile * 32 + cl * 8 + quad * 2;
      #pragma unroll
      for (int mt = 0; mt < 3; ++mt) {
        const uint2 wb = *(const uint2*)&binsw[p_mt[mt] * BSW_ + widx];
        const uint2 m0 = oh4(wb.x, kb4_mt[mt]);
        const uint2 m1 = oh4(wb.y, kb4_mt[mt]);
        const half8 af = __builtin_bit_cast(half8, make_uint4(m0.x, m0.y, m1.x, m1.y));
        acch[mt][0] = __builtin_amdgcn_mfma_f32_16x16x32_f16(af, bh0, acch[mt][0], 0, 0, 0);
        accl[mt][0] = __builtin_amdgcn_mfma_f32_16x16x32_f16(af, bl0, accl[mt][0], 0, 0, 0);
        acch[mt][1] = __builtin_amdgcn_mfma_f32_16x16x32_f16(af, bh1, acch[mt][1], 0, 0, 0);
        accl[mt][1] = __builtin_amdgcn_mfma_f32_16x16x32_f16(af, bl1, accl[mt][1], 0, 0, 0);
      }
    }
    __syncthreads();   // all reads done before next tile's staging overwrite
  }

  // combine hi + lo/4096
  f32x4 acc[3][2];
  #pragma unroll
  for (int mt = 0; mt < 3; ++mt) {
    acc[mt][0] = acch[mt][0] + accl[mt][0] * 2.44140625e-4f;
    acc[mt][1] = acch[mt][1] + accl[mt][1] * 2.44140625e-4f;
  }

  // k-half combine via red (aliases bins/amp; barrier above protects).
  // C/D layout: col = lane&15, row = quad*4 + reg.
  if (q2 == 1) {
    float* S = &red[mq * 48 * 33];
    #pragma unroll
    for (int mt = 0; mt < 3; ++mt)
      #pragma unroll
      for (int n = 0; n < 2; ++n)
        #pragma unroll
        for (int r = 0; r < 4; ++r)
          S[(mt * 16 + quad * 4 + r) * 33 + n * 16 + lc] = acc[mt][n][r];
  }
  __syncthreads();
  if (q2 == 0) {
    float* S = &red[mq * 48 * 33];
    float* W = ws + (long)bid * 6144;
    #pragma unroll
    for (int mt = 0; mt < 3; ++mt)
      #pragma unroll
      for (int n = 0; n < 2; ++n)
        #pragma unroll
        for (int r = 0; r < 4; ++r) {
          const float v = acc[mt][n][r] + S[(mt * 16 + quad * 4 + r) * 33 + n * 16 + lc];
          W[(mq * 48 + mt * 16 + quad * 4 + r) * 32 + n * 16 + lc] = v;
        }
  }
}

// Epilogue: one block per (bc, p). Stage 16x576 partials coalesced into LDS,
// 120 threads (s,a) compute entropy, 30 threads reduce over s.
__global__ __launch_bounds__(256)
void mi_ent(const float* __restrict__ ws, float* __restrict__ out) {
  __shared__ float tbl[16 * 576];
  __shared__ float red[4][32];
  const int bc = blockIdx.x / FP_;
  const int p  = blockIdx.x - bc * FP_;
  const int tid = threadIdx.x;

  #pragma unroll
  for (int it = 0; it < 36; ++it) {
    const int i = it * 256 + tid;
    const int sub = i / 576, r = i - sub * 576;
    tbl[i] = ws[(long)(bc * 16 + sub) * 6144 + p * 576 + r];
  }
  __syncthreads();

  if (tid < 120) {
    const int s = tid / FA_;
    const int a = tid - s * FA_;
    const float* t0 = &tbl[(s * 4 + 0) * 576];
    const float* t1 = &tbl[(s * 4 + 1) * 576];
    const float* t2 = &tbl[(s * 4 + 2) * 576];
    const float* t3 = &tbl[(s * 4 + 3) * 576];
    float m[K_];
    float tot = 0.0f;
    #pragma unroll
    for (int k = 0; k < K_; ++k) {
      const float cnt = (t0[k*32+30] + t1[k*32+30]) + (t2[k*32+30] + t3[k*32+30]);
      const float sv  = (t0[k*32+a]  + t1[k*32+a])  + (t2[k*32+a]  + t3[k*32+a]);
      const float mk  = sv / (cnt + 1e-9f);
      m[k] = mk;
      tot += mk;
    }
    const float denom = tot + 1e-9f;
    float ent = 0.0f;
    #pragma unroll
    for (int k = 0; k < K_; ++k) {
      const float pr = m[k] / denom;
      ent += pr * logf(pr + 1e-9f);
    }
    const float L = logf(18.0f);
    red[s][a] = (L + ent) / L;
  }
  __syncthreads();
  if (tid < FA_)
    out[(bc * FP_ + p) * FA_ + tid] =
        0.25f * (red[0][tid] + red[1][tid] + red[2][tid] + red[3][tid]);
}

extern "C" void kernel_launch(void* const* d_in, const int* in_sizes, int n_in,
                              void* d_out, int out_size, void* d_ws, size_t ws_size,
                              hipStream_t stream) {
  const float* pha = (const float*)d_in[0];
  const float* amp = (const float*)d_in[1];
  float* out = (float*)d_out;
  float* ws  = (float*)d_ws;   // 1024 * 6144 f32 = 25.2 MB partials

  hipLaunchKernelGGL(mi_main, dim3(1024), dim3(NT_), LDS_BYTES, stream, pha, amp, ws);
  hipLaunchKernelGGL(mi_ent, dim3(64 * FP_), dim3(256), 0, stream, ws, out);
}

// Round 6
// 112.205 us; speedup vs baseline: 2.6151x; 2.6151x over previous
//
#include <hip/hip_runtime.h>
#include <math.h>

// ModulationIndex as i8 MFMA GEMM, v6.
// amp_sums[p*18+k, a] = sum_t onehot[pk, t] * amp[a, t]
// amp quantized q = floor(amp*65536) as u16 -> lo/hi byte planes (bias -128),
// two i32_16x16x64_i8 MFMAs per K=64 chunk; exact integer reconstruction in
// epilogue: sum_q = 256*acc_h + acc_l + 32896*cnt (cnt from ones column, no bias).
// Grid 512 = (group, t-half); 512 thr; ~28KB LDS; 8 waves = 4 mq x 2 khalf.

#define FP_ 10
#define FA_ 30
#define K_  18
#define T_  2048
#define TH_ 1024
#define TC_ 256
#define NTILE 4
#define NT_ 512

#define OFF_BINS 128
#define BINROW   1040                      // bytes per bins row (1024+16)
#define BSW_     260                       // words per bins row
#define OFF_LO   (OFF_BINS + FP_ * BINROW) // 10528
#define PROW     272                       // bytes per plane row (256+16; odd 16B units)
#define PLSZ     (32 * PROW)               // 8704
#define OFF_HI   (OFF_LO + PLSZ)           // 19232
#define LDS_TOTAL (OFF_HI + PLSZ)          // 27936
#define OFF_RED  128                       // alias over bins+lo after K-loop
#define OFF_CNT  (OFF_RED + 192 * 33 * 4)  // 25472; +1536 = 27008 < 27936

typedef int i32x4 __attribute__((ext_vector_type(4)));

// 0x01 at bytes of w equal to the replicated byte kb4 (zero-byte trick).
static __device__ __forceinline__ unsigned oh8(unsigned w, unsigned kb4) {
  const unsigned x = w ^ kb4;
  const unsigned t = (x & 0x7F7F7F7Fu) + 0x7F7F7F7Fu;
  return ((~(t | x)) & 0x80808080u) >> 7;
}

__global__ __launch_bounds__(NT_, 4)
void mi_main(const float* __restrict__ pha, const float* __restrict__ amp,
             float* __restrict__ ws) {
  extern __shared__ unsigned char smem[];
  float*    c_lds = (float*)smem;
  unsigned* binsw = (unsigned*)(smem + OFF_BINS);
  float*    red   = (float*)(smem + OFF_RED);
  int*      cnt_t = (int*)(smem + OFF_CNT);

  const int tid  = threadIdx.x;
  const int lane = tid & 63;
  const int wv   = tid >> 6;
  const int quad = lane >> 4;
  const int lc   = lane & 15;
  const int mq   = wv & 3;    // m-quarter: rows mq*48..+47
  const int q2   = wv >> 2;   // k-half

  const int bid  = blockIdx.x;
  const int g    = bid >> 1;
  const int half = bid & 1;
  const int s    = g & 3;
  const int bc   = g >> 2;
  const long pha_base = (long)bc * (FP_ * 4L * T_) + (long)s * T_ + half * TH_;
  const long amp_base = (long)bc * (FA_ * 4L * T_) + (long)s * T_ + half * TH_;

  // cutoffs: bit-exact np.linspace(-pi, pi, 19) (f64 math, f32 cast)
  if (tid < 19) {
    const double PI_D = 3.14159265358979323846264338327950288;
    const double step = (2.0 * PI_D) / 18.0;
    c_lds[tid] = (tid == 18) ? (float)PI_D : (float)(-PI_D + (double)tid * step);
  }
  // static plane rows: 30 = ones in lo (counts, unbiased), zeros elsewhere
  if (tid < 17) {
    *(uint4*)(smem + OFF_LO + 30 * PROW + tid * 16) =
        make_uint4(0x01010101u, 0x01010101u, 0x01010101u, 0x01010101u);
    *(uint4*)(smem + OFF_LO + 31 * PROW + tid * 16) = make_uint4(0u, 0u, 0u, 0u);
    *(uint4*)(smem + OFF_HI + 30 * PROW + tid * 16) = make_uint4(0u, 0u, 0u, 0u);
    *(uint4*)(smem + OFF_HI + 31 * PROW + tid * 16) = make_uint4(0u, 0u, 0u, 0u);
  }

  // issue tile-0 amp loads first (latency hides under bins phase)
  const bool stager = tid < 480;
  const int a_row = tid >> 4;
  const int seg   = tid & 15;            // 16-t unit within tile
  const float* gsrc = amp + amp_base + (long)a_row * (4L * T_) + seg * 16;
  float4 vreg[4];
  if (stager) {
    #pragma unroll
    for (int j = 0; j < 4; ++j) vreg[j] = *(const float4*)(gsrc + j * 4);
  }

  // --- bins: 2560 u32 words (u8 bins, 4 t each)
  const float PI_F    = 3.14159274101257324f;
  const float INVSTEP = 2.8647890f;
  #pragma unroll
  for (int it = 0; it < 5; ++it) {
    const int i = it * NT_ + tid;
    const int p = i >> 8, w = i & 255;
    const float4 v = *(const float4*)(pha + pha_base + (long)p * (4L * T_) + w * 4);
    const float xs[4] = {v.x, v.y, v.z, v.w};
    unsigned pk = 0;
    #pragma unroll
    for (int j = 0; j < 4; ++j) {
      const float x = xs[j];
      int gi = (int)((x + PI_F) * INVSTEP);
      gi = min(17, max(0, gi));
      if (x <= c_lds[gi]) gi -= 1;        // searchsorted-left: c_b < x <= c_{b+1}
      else if (x > c_lds[gi + 1]) gi += 1;
      gi = min(17, max(0, gi));
      pk |= ((unsigned)gi) << (8 * j);
    }
    binsw[p * BSW_ + w] = pk;
  }

  // per-wave A-row tables (A operand: m = lane&15)
  int p_mt[3]; unsigned kb4_mt[3];
  #pragma unroll
  for (int mt = 0; mt < 3; ++mt) {
    const int row = mq * 48 + mt * 16 + lc;
    int p = row / 18; p = min(p, 9);
    const unsigned kb = (unsigned)(row - p * 18);   // >=18 on pad rows
    p_mt[mt] = p;
    kb4_mt[mt] = kb * 0x01010101u;
  }

  i32x4 accl[3][2], acch[3][2];
  #pragma unroll
  for (int mt = 0; mt < 3; ++mt) {
    accl[mt][0] = (i32x4){0,0,0,0}; accl[mt][1] = (i32x4){0,0,0,0};
    acch[mt][0] = (i32x4){0,0,0,0}; acch[mt][1] = (i32x4){0,0,0,0};
  }
  __syncthreads();   // bins + cutoffs + const rows visible

  #pragma unroll 1
  for (int tile = 0; tile < NTILE; ++tile) {
    if (stager) {   // quantize + byte-split + write 16 t into both planes
      unsigned lo[4], hi[4];
      #pragma unroll
      for (int j = 0; j < 4; ++j) {
        const float xv[4] = {vreg[j].x, vreg[j].y, vreg[j].z, vreg[j].w};
        unsigned q[4];
        #pragma unroll
        for (int e = 0; e < 4; ++e)
          q[e] = min((unsigned)(xv[e] * 65536.0f), 65535u);
        const unsigned w01 = q[0] | (q[1] << 16);
        const unsigned w23 = q[2] | (q[3] << 16);
        lo[j] = __builtin_amdgcn_perm(w23, w01, 0x06040200u) ^ 0x80808080u;
        hi[j] = __builtin_amdgcn_perm(w23, w01, 0x07050301u) ^ 0x80808080u;
      }
      *(uint4*)(smem + OFF_LO + a_row * PROW + seg * 16) = make_uint4(lo[0], lo[1], lo[2], lo[3]);
      *(uint4*)(smem + OFF_HI + a_row * PROW + seg * 16) = make_uint4(hi[0], hi[1], hi[2], hi[3]);
    }
    __syncthreads();
    if (stager && tile < NTILE - 1) {   // prefetch next tile during compute
      #pragma unroll
      for (int j = 0; j < 4; ++j)
        vreg[j] = *(const float4*)(gsrc + (tile + 1) * TC_ + j * 4);
    }

    #pragma unroll
    for (int ci = 0; ci < 2; ++ci) {
      const int cl = q2 * 2 + ci;                 // 64-t chunk 0..3 in tile
      const unsigned char* bl = smem + OFF_LO + cl * 64 + quad * 16;
      const unsigned char* bh = smem + OFF_HI + cl * 64 + quad * 16;
      const i32x4 Bl0 = *(const i32x4*)(bl + lc * PROW);
      const i32x4 Bl1 = *(const i32x4*)(bl + (16 + lc) * PROW);
      const i32x4 Bh0 = *(const i32x4*)(bh + lc * PROW);
      const i32x4 Bh1 = *(const i32x4*)(bh + (16 + lc) * PROW);
      const int chg = tile * 4 + cl;              // global 64-t chunk
      #pragma unroll
      for (int mt = 0; mt < 3; ++mt) {
        const uint4 wb = *(const uint4*)(smem + OFF_BINS + p_mt[mt] * BINROW
                                         + chg * 64 + quad * 16);
        const unsigned kb4 = kb4_mt[mt];
        const i32x4 A = (i32x4){(int)oh8(wb.x, kb4), (int)oh8(wb.y, kb4),
                                (int)oh8(wb.z, kb4), (int)oh8(wb.w, kb4)};
        accl[mt][0] = __builtin_amdgcn_mfma_i32_16x16x64_i8(A, Bl0, accl[mt][0], 0, 0, 0);
        acch[mt][0] = __builtin_amdgcn_mfma_i32_16x16x64_i8(A, Bh0, acch[mt][0], 0, 0, 0);
        accl[mt][1] = __builtin_amdgcn_mfma_i32_16x16x64_i8(A, Bl1, accl[mt][1], 0, 0, 0);
        acch[mt][1] = __builtin_amdgcn_mfma_i32_16x16x64_i8(A, Bh1, acch[mt][1], 0, 0, 0);
      }
    }
    __syncthreads();   // reads done before next tile's staging overwrite
  }

  // --- counts table (col 30 lives at n=1, lc=14); C layout: row=quad*4+r, col=n*16+lc
  if (lc == 14) {
    #pragma unroll
    for (int mt = 0; mt < 3; ++mt)
      #pragma unroll
      for (int r = 0; r < 4; ++r)
        cnt_t[q2 * 192 + mq * 48 + mt * 16 + quad * 4 + r] = accl[mt][1][r];
  }
  __syncthreads();

  // exact reconstruction to f32 per-half sums
  float vals[3][2][4];
  #pragma unroll
  for (int mt = 0; mt < 3; ++mt)
    #pragma unroll
    for (int n = 0; n < 2; ++n)
      #pragma unroll
      for (int r = 0; r < 4; ++r) {
        const int row = mq * 48 + mt * 16 + quad * 4 + r;
        const int cnt = cnt_t[q2 * 192 + row];
        const int raw = (acch[mt][n][r] << 8) + accl[mt][n][r] + 32896 * cnt;
        float v = (float)raw * 1.52587890625e-5f;   // / 65536
        if (n == 1 && lc == 14) v = (float)accl[mt][n][r];   // counts column raw
        vals[mt][n][r] = v;
      }
  __syncthreads();   // cnt reads done before red (disjoint, but keep ordering simple)

  // k-half combine via red, then write f32 partials
  if (q2 == 1) {
    float* S = &red[mq * 48 * 33];
    #pragma unroll
    for (int mt = 0; mt < 3; ++mt)
      #pragma unroll
      for (int n = 0; n < 2; ++n)
        #pragma unroll
        for (int r = 0; r < 4; ++r)
          S[(mt * 16 + quad * 4 + r) * 33 + n * 16 + lc] = vals[mt][n][r];
  }
  __syncthreads();
  if (q2 == 0) {
    float* S = &red[mq * 48 * 33];
    float* W = ws + (long)bid * 6144;
    #pragma unroll
    for (int mt = 0; mt < 3; ++mt)
      #pragma unroll
      for (int n = 0; n < 2; ++n)
        #pragma unroll
        for (int r = 0; r < 4; ++r) {
          const float v = vals[mt][n][r] + S[(mt * 16 + quad * 4 + r) * 33 + n * 16 + lc];
          W[(mq * 48 + mt * 16 + quad * 4 + r) * 32 + n * 16 + lc] = v;
        }
  }
}

// Epilogue: one block per (bc, p). Stage 8x576 partials coalesced into LDS,
// 120 threads (s,a) compute entropy, 30 threads reduce over s.
__global__ __launch_bounds__(256)
void mi_ent(const float* __restrict__ ws, float* __restrict__ out) {
  __shared__ float tbl[8 * 576];
  __shared__ float red[4][32];
  const int bc = blockIdx.x / FP_;
  const int p  = blockIdx.x - bc * FP_;
  const int tid = threadIdx.x;

  #pragma unroll
  for (int it = 0; it < 18; ++it) {
    const int i = it * 256 + tid;
    const int sub = i / 576, r = i - sub * 576;
    tbl[i] = ws[(long)(bc * 8 + sub) * 6144 + p * 576 + r];
  }
  __syncthreads();

  if (tid < 120) {
    const int s = tid / FA_;
    const int a = tid - s * FA_;
    const float* t0 = &tbl[(2 * s) * 576];
    const float* t1 = &tbl[(2 * s + 1) * 576];
    float m[K_];
    float tot = 0.0f;
    #pragma unroll
    for (int k = 0; k < K_; ++k) {
      const float cnt = t0[k * 32 + 30] + t1[k * 32 + 30];
      const float sv  = t0[k * 32 + a]  + t1[k * 32 + a];
      const float mk  = sv / (cnt + 1e-9f);
      m[k] = mk;
      tot += mk;
    }
    const float denom = tot + 1e-9f;
    float ent = 0.0f;
    #pragma unroll
    for (int k = 0; k < K_; ++k) {
      const float pr = m[k] / denom;
      ent += pr * logf(pr + 1e-9f);
    }
    const float L = logf(18.0f);
    red[s][a] = (L + ent) / L;
  }
  __syncthreads();
  if (tid < FA_)
    out[(bc * FP_ + p) * FA_ + tid] =
        0.25f * (red[0][tid] + red[1][tid] + red[2][tid] + red[3][tid]);
}

extern "C" void kernel_launch(void* const* d_in, const int* in_sizes, int n_in,
                              void* d_out, int out_size, void* d_ws, size_t ws_size,
                              hipStream_t stream) {
  const float* pha = (const float*)d_in[0];
  const float* amp = (const float*)d_in[1];
  float* out = (float*)d_out;
  float* ws  = (float*)d_ws;   // 512 * 6144 f32 = 12.6 MB partials

  hipLaunchKernelGGL(mi_main, dim3(512), dim3(NT_), LDS_TOTAL, stream, pha, amp, ws);
  hipLaunchKernelGGL(mi_ent, dim3(64 * FP_), dim3(256), 0, stream, ws, out);
}